// Round 2
// baseline (42609.106 us; speedup 1.0000x reference)
//
#include <hip/hip_runtime.h>
#include <hip/hip_bf16.h>
#include <math.h>

// Problem constants
#define EMB 400
#define HID 300
#define KEY 128
#define VAL 128
#define VOCAB 33
#define T_STEPS 256
#define B 256
#define S 512
#define KT 428        // gates K: ctx(128)+h(300); logits K: h(300)+ctx(128) — both 428
#define GATES 1200    // 4*HID
#define NCHUNK 8      // s-chunks for flash-style attention
#define CS 64         // chunk size (S / NCHUNK)
#define PSTRIDE 132   // partial record: 128 pctx + m + S (+pad)

__device__ __forceinline__ float sigmoidf_(float x) {
    return 1.f / (1.f + expf(-x));
}

// ---------------- Precompute: E2[v][j] = b_ih[j] + b_hh[j] + sum_e emb[v][e]*W_ih[j][e]
__global__ __launch_bounds__(256) void p1_e2(
    const float* __restrict__ emb, const float* __restrict__ Wih,
    const float* __restrict__ bih, const float* __restrict__ bhh,
    float* __restrict__ E2)
{
    __shared__ float es[EMB];
    const int v = blockIdx.x;
    for (int i = threadIdx.x; i < EMB; i += 256) es[i] = emb[v * EMB + i];
    __syncthreads();
    for (int j = threadIdx.x; j < GATES; j += 256) {
        float s = bih[j] + bhh[j];
        const float* wr = &Wih[(size_t)j * (EMB + VAL)];
        #pragma unroll 4
        for (int e = 0; e < EMB; ++e) s += es[e] * wr[e];
        E2[v * GATES + j] = s;
    }
}

// ---------------- Precompute: phi_w transpose, proj_w transpose, h/c init broadcast
__global__ __launch_bounds__(256) void p2_init(
    const float* __restrict__ phi_w, const float* __restrict__ projw,
    const float* __restrict__ h0, const float* __restrict__ c0,
    float* __restrict__ phi_wT, float* __restrict__ projwT,
    float* __restrict__ h, float* __restrict__ c)
{
    int i = blockIdx.x * 256 + threadIdx.x;
    if (i < KEY * HID) {
        int k = i / HID, ii = i % HID;        // phi_w[k][ii]
        phi_wT[ii * KEY + k] = phi_w[i];
    }
    if (i < VOCAB * KT) {
        int k = i / VOCAB, v = i - k * VOCAB; // projwT[k][v] = projw[v][k]
        projwT[k * VOCAB + v] = projw[v * KT + k];
    }
    if (i < B * HID) {
        int ii = i % HID;
        h[i] = h0[ii];
        c[i] = c0[ii];
    }
}

// ---------------- K1: fused gates GEMM + LSTM cell update (fp32)
#define TB 16
#define TN 16
#define BK 32
__global__ __launch_bounds__(256) void k1_lstm(
    const int* __restrict__ xt,        // B ints for this step
    const float* __restrict__ Wih,     // [1200][528]
    const float* __restrict__ Whh,     // [1200][300]
    const float* __restrict__ E2,      // [33][1200]
    const float* __restrict__ ctx,     // [256][128]  (ctx(t-1))
    const float* __restrict__ h_in,    // [256][300]
    float* __restrict__ h_out,         // [256][300]
    float* __restrict__ c)             // [256][300] in-place
{
    __shared__ float As[TB][BK + 1];
    __shared__ float Ws[4][TN][BK + 1];
    const int tid = threadIdx.x;
    const int nl = tid & 15;
    const int bl = tid >> 4;
    const int b0 = blockIdx.x * TB;
    const int n0 = blockIdx.y * TN;
    const int b = b0 + bl;
    const int n = n0 + nl;
    const bool valid = (n < HID);

    const int xb = xt[b];
    float acc[4];
    #pragma unroll
    for (int g = 0; g < 4; ++g)
        acc[g] = valid ? E2[xb * GATES + g * HID + n] : 0.f;

    for (int k0 = 0; k0 < KT; k0 += BK) {
        #pragma unroll
        for (int r = 0; r < 2; ++r) {
            int e = r * 256 + tid;
            int bb = e >> 5, kk = e & 31;
            int k = k0 + kk;
            float vv = 0.f;
            if (k < KT) {
                int gb = b0 + bb;
                vv = (k < VAL) ? ctx[gb * VAL + k] : h_in[gb * HID + (k - VAL)];
            }
            As[bb][kk] = vv;
        }
        #pragma unroll
        for (int r = 0; r < 8; ++r) {
            int e = r * 256 + tid;
            int g = e >> 9;
            int rem = e & 511;
            int nn = rem >> 5, kk = rem & 31;
            int k = k0 + kk;
            int jn = n0 + nn;
            float vv = 0.f;
            if (k < KT && jn < HID) {
                int j = g * HID + jn;
                vv = (k < VAL) ? Wih[(size_t)j * (EMB + VAL) + EMB + k]
                               : Whh[(size_t)j * HID + (k - VAL)];
            }
            Ws[g][nn][kk] = vv;
        }
        __syncthreads();
        #pragma unroll
        for (int kk = 0; kk < BK; ++kk) {
            float a = As[bl][kk];
            #pragma unroll
            for (int g = 0; g < 4; ++g) acc[g] += a * Ws[g][nl][kk];
        }
        __syncthreads();
    }

    if (valid) {
        float ig = sigmoidf_(acc[0]);
        float fg = sigmoidf_(acc[1]);
        float gg = tanhf(acc[2]);
        float og = sigmoidf_(acc[3]);
        float cn = fg * c[b * HID + n] + ig * gg;
        c[b * HID + n] = cn;
        h_out[b * HID + n] = og * tanhf(cn);
    }
}

// ---------------- K2a: flash-style attention partial per (b, s-chunk)
// grid (B, NCHUNK), 256 threads. Computes q (redundantly per chunk), 64
// energies, local max/expsum, partial ctx over the chunk. Writes
// [pctx(128), m, S] to ws.
__global__ __launch_bounds__(256) void k2a_attn(
    const float* __restrict__ keys,     // [512][256][128]
    const float* __restrict__ values,   // [512][256][128]
    const float* __restrict__ phi_wT,   // [300][128]
    const float* __restrict__ phi_b,    // [128]
    const float* __restrict__ h,        // [256][300]  (new h)
    float* __restrict__ partial)        // [B*NCHUNK][PSTRIDE]
{
    __shared__ float hh[HID];
    __shared__ __align__(16) float q[KEY];
    __shared__ float en[CS];
    __shared__ float cp[2][VAL];
    __shared__ float mS[2];

    const int t = threadIdx.x;
    const int b = blockIdx.x;
    const int chunk = blockIdx.y;
    const int s0 = chunk * CS;

    for (int i = t; i < HID; i += 256) hh[i] = h[b * HID + i];
    __syncthreads();

    // q[k] = phi_b[k] + sum_i hh[i] * phi_wT[i][k]   (threads 0..127)
    if (t < KEY) {
        float s = phi_b[t];
        #pragma unroll 4
        for (int i = 0; i < HID; ++i) s += hh[i] * phi_wT[i * KEY + t];
        q[t] = s;
    }
    __syncthreads();

    // energies for 64 s-values: 16 lanes per s, float4 loads
    {
        const int lane16 = t & 15;
        const int grp = t >> 4;                  // 0..15
        const float4* q4 = reinterpret_cast<const float4*>(q);
        float4 q0 = q4[lane16 * 2], q1 = q4[lane16 * 2 + 1];
        #pragma unroll
        for (int it = 0; it < 4; ++it) {
            int sl = it * 16 + grp;
            const float4* kp = reinterpret_cast<const float4*>(
                &keys[((size_t)(s0 + sl) * B + b) * KEY]);
            float4 k0 = kp[lane16 * 2], k1 = kp[lane16 * 2 + 1];
            float e = k0.x * q0.x + k0.y * q0.y + k0.z * q0.z + k0.w * q0.w
                    + k1.x * q1.x + k1.y * q1.y + k1.z * q1.z + k1.w * q1.w;
            e += __shfl_xor(e, 1);
            e += __shfl_xor(e, 2);
            e += __shfl_xor(e, 4);
            e += __shfl_xor(e, 8);
            if (lane16 == 0) en[sl] = e;
        }
    }
    __syncthreads();

    // local softmax partials over 64 energies (one wave)
    if (t < CS) {
        float e = en[t];
        float m = e;
        #pragma unroll
        for (int off = 32; off; off >>= 1) m = fmaxf(m, __shfl_xor(m, off));
        float p = expf(e - m);
        float ss = p;
        #pragma unroll
        for (int off = 32; off; off >>= 1) ss += __shfl_xor(ss, off);
        en[t] = p;
        if (t == 0) { mS[0] = m; mS[1] = ss; }
    }
    __syncthreads();

    // partial ctx: pctx[v] = sum_{s in chunk} p[s] * values[s][b][v]
    {
        int v = t & 127, half = t >> 7;
        float a = 0.f;
        int sl0 = half * 32;
        #pragma unroll 4
        for (int sl = sl0; sl < sl0 + 32; ++sl)
            a += en[sl] * values[((size_t)(s0 + sl) * B + b) * VAL + v];
        cp[half][v] = a;
    }
    __syncthreads();

    float* P = &partial[(size_t)(b * NCHUNK + chunk) * PSTRIDE];
    if (t < VAL) P[t] = cp[0][t] + cp[1][t];
    else if (t == VAL) P[VAL] = mS[0];
    else if (t == VAL + 1) P[VAL + 1] = mS[1];
}

// ---------------- K2b: combine partials -> ctx_out; fused logits (old ctx)
// grid B, 256 threads.
__global__ __launch_bounds__(256) void k2b_combine(
    const float* __restrict__ partial,  // [B*NCHUNK][PSTRIDE]
    const float* __restrict__ h,        // [256][300] (new h)
    const float* __restrict__ ctx_in,   // [256][128] (old ctx, for logits)
    const float* __restrict__ projwT,   // [428][33]
    const float* __restrict__ projb,    // [33]
    float* __restrict__ ctx_out,        // [256][128]
    float* __restrict__ out,            // &logits[t][0][0] or nullptr
    int do_ctx)
{
    __shared__ float hh[HID];
    __shared__ float cx[VAL];
    __shared__ float wj[NCHUNK];

    const int t = threadIdx.x;
    const int b = blockIdx.x;

    if (out != nullptr) {
        for (int i = t; i < HID; i += 256) hh[i] = h[b * HID + i];
        if (t < VAL) cx[t] = ctx_in[b * VAL + t];
    }
    if (do_ctx && t == 0) {
        float mj[NCHUNK], Sj[NCHUNK];
        float M = -1e30f;
        #pragma unroll
        for (int j = 0; j < NCHUNK; ++j) {
            const float* P = &partial[(size_t)(b * NCHUNK + j) * PSTRIDE];
            mj[j] = P[VAL]; Sj[j] = P[VAL + 1];
            M = fmaxf(M, mj[j]);
        }
        float T = 0.f;
        #pragma unroll
        for (int j = 0; j < NCHUNK; ++j) T += Sj[j] * expf(mj[j] - M);
        float invT = 1.f / T;
        #pragma unroll
        for (int j = 0; j < NCHUNK; ++j) wj[j] = expf(mj[j] - M) * invT;
    }
    __syncthreads();

    if (do_ctx && t < VAL) {
        float s = 0.f;
        #pragma unroll
        for (int j = 0; j < NCHUNK; ++j)
            s += wj[j] * partial[(size_t)(b * NCHUNK + j) * PSTRIDE + t];
        ctx_out[b * VAL + t] = s;
    }

    if (out != nullptr && t >= 128 && t < 128 + VOCAB) {
        int v = t - 128;
        float s = projb[v];
        #pragma unroll 4
        for (int k = 0; k < KT; ++k) {
            float a = (k < HID) ? hh[k] : cx[k - HID];
            s += a * projwT[k * VOCAB + v];
        }
        out[b * VOCAB + v] = s;
    }
}

extern "C" void kernel_launch(void* const* d_in, const int* in_sizes, int n_in,
                              void* d_out, int out_size, void* d_ws, size_t ws_size,
                              hipStream_t stream)
{
    const int*   input     = (const int*)  d_in[0];   // [T][B]
    const float* keys      = (const float*)d_in[1];   // [S][B][KEY]
    const float* values    = (const float*)d_in[2];   // [S][B][VAL]
    const float* embedding = (const float*)d_in[3];   // [VOCAB][EMB]
    const float* phi_w     = (const float*)d_in[4];   // [KEY][HID]
    const float* phi_b     = (const float*)d_in[5];   // [KEY]
    const float* h0        = (const float*)d_in[6];   // [1][HID]
    const float* c0        = (const float*)d_in[7];   // [1][HID]
    const float* W_ih      = (const float*)d_in[8];   // [1200][528]
    const float* b_ih      = (const float*)d_in[9];
    const float* W_hh      = (const float*)d_in[10];  // [1200][300]
    const float* b_hh      = (const float*)d_in[11];
    const float* proj_w    = (const float*)d_in[12];  // [33][428]
    const float* proj_b    = (const float*)d_in[13];
    float* out = (float*)d_out;

    float* ws = (float*)d_ws;
    float* hA      = ws;                        // 256*300
    float* hB      = hA + B * HID;              // 256*300
    float* c       = hB + B * HID;              // 256*300
    float* ctxA    = c + B * HID;               // 256*128
    float* ctxB    = ctxA + B * VAL;            // 256*128
    float* E2      = ctxB + B * VAL;            // 33*1200
    float* phi_wT  = E2 + VOCAB * GATES;        // 300*128
    float* projwT  = phi_wT + HID * KEY;        // 428*33
    float* partial = projwT + KT * VOCAB;       // 2048*132

    float* ctx_buf[2] = { ctxA, ctxB };

    p1_e2<<<VOCAB, 256, 0, stream>>>(embedding, W_ih, b_ih, b_hh, E2);
    p2_init<<<(B * HID + 255) / 256, 256, 0, stream>>>(
        phi_w, proj_w, h0, c0, phi_wT, projwT, hA, c);

    // initial ctx(-1) = attend(h_init) -> ctx_buf[0]; no logits
    k2a_attn<<<dim3(B, NCHUNK), 256, 0, stream>>>(keys, values, phi_wT, phi_b,
                                                  hA, partial);
    k2b_combine<<<B, 256, 0, stream>>>(partial, hA, ctx_buf[0], projwT, proj_b,
                                       ctx_buf[0], nullptr, 1);

    float* hin = hA;
    float* hout = hB;
    for (int t = 0; t < T_STEPS; ++t) {
        float* ctx_in  = ctx_buf[t & 1];
        float* ctx_out = ctx_buf[(t + 1) & 1];
        k1_lstm<<<dim3(B / TB, (HID + TN - 1) / TN), 256, 0, stream>>>(
            input + t * B, W_ih, W_hh, E2, ctx_in, hin, hout, c);
        int do_ctx = (t < T_STEPS - 1) ? 1 : 0;
        if (do_ctx)
            k2a_attn<<<dim3(B, NCHUNK), 256, 0, stream>>>(keys, values, phi_wT,
                                                          phi_b, hout, partial);
        k2b_combine<<<B, 256, 0, stream>>>(partial, hout, ctx_in, projwT, proj_b,
                                           ctx_out, out + (size_t)t * B * VOCAB,
                                           do_ctx);
        float* tmp = hin; hin = hout; hout = tmp;
    }
}

// Round 4
// 34684.387 us; speedup vs baseline: 1.2285x; 1.2285x over previous
//
#include <hip/hip_runtime.h>
#include <hip/hip_bf16.h>
#include <hip/hip_cooperative_groups.h>
#include <math.h>

namespace cg = cooperative_groups;

// Problem constants
#define EMBD 400
#define HIDD 300
#define KEYD 128
#define VALD 128
#define NVOC 33
#define TT 256
#define BB 256
#define SS 512
#define WIH_LD 528          // EMB+VAL
#define GDIM 1200           // 4*HID
#define KTOT 428            // ctx(128)+h(300)
#define PSTRIDE 132         // partial record: 128 pctx + m + S (+pad)
#define NGRID 512           // 2 blocks/CU — co-residency with big margin

// gates tiling: TB=32 b x TN=16 n per block, 2 b-rows per thread
#define GTB 32
#define GTN 16
#define GBK 32
#define N_BT (BB / GTB)                 // 8
#define N_NT ((HIDD + GTN - 1) / GTN)   // 19
#define N_GATES (N_BT * N_NT)           // 152

__device__ __forceinline__ float sigmoidf_(float x) {
    return 1.f / (1.f + expf(-x));
}

struct __align__(16) SharedAll {
    union {
        struct {                          // P0: E2 precompute
            float es[EMBD];
        } p;
        struct {                          // gates phase
            float ctx_s[GTB][KEYD];       // 16 KB, persists through K-loop
            union {
                struct { float m[GTB][8]; float S[GTB][8]; float w[GTB][8]; } c;
                struct { float As[GTB][GBK + 1]; float Ws[4][GTN][GBK + 1]; } k;
            } u;
        } g;
        struct {                          // logits phase
            float hrow[HIDD]; float crow[VALD]; float lp[NVOC][8];
        } l;
        struct {                          // attention phase
            float q[KEYD];                // first => 16B aligned
            float hh[HIDD];
            float en[64];
            float cp[2][VALD];
            float mS[2];
        } b;
    };
};

// ---------------- attention phase: 1 block = 1 b x 4 s-chunks ----------------
__device__ void attn_phase(SharedAll& sh, int bid, int tid,
                           const float* __restrict__ keys,
                           const float* __restrict__ values,
                           const float* phi_wT, const float* __restrict__ phi_b,
                           const float* h, float* partial)
{
    const int b = bid & 255;
    const int c0 = bid >> 8;              // 0..1; chunks {c0, c0+2, c0+4, c0+6}

    for (int i = tid; i < HIDD; i += 256) sh.b.hh[i] = h[b * HIDD + i];
    __syncthreads();

    // q[k] = phi_b[k] + sum_i hh[i]*phi_wT[i][k]
    if (tid < KEYD) {
        float s = phi_b[tid];
        #pragma unroll 4
        for (int i = 0; i < HIDD; ++i) s += sh.b.hh[i] * phi_wT[i * KEYD + tid];
        sh.b.q[tid] = s;
    }
    __syncthreads();

    const int lane16 = tid & 15;
    const int grp = tid >> 4;             // 0..15
    const float4* q4 = reinterpret_cast<const float4*>(sh.b.q);
    const float4 q0 = q4[lane16 * 2], q1 = q4[lane16 * 2 + 1];

    #pragma unroll 1
    for (int ci = 0; ci < 4; ++ci) {
        const int chunk = c0 + ci * 2;
        const int s0 = chunk * 64;

        // 64 energies: 16 lanes per s, float4 loads
        #pragma unroll
        for (int it = 0; it < 4; ++it) {
            int sl = it * 16 + grp;
            const float4* kp = reinterpret_cast<const float4*>(
                &keys[((size_t)(s0 + sl) * BB + b) * KEYD]);
            float4 k0 = kp[lane16 * 2], k1 = kp[lane16 * 2 + 1];
            float e = k0.x * q0.x + k0.y * q0.y + k0.z * q0.z + k0.w * q0.w
                    + k1.x * q1.x + k1.y * q1.y + k1.z * q1.z + k1.w * q1.w;
            e += __shfl_xor(e, 1);
            e += __shfl_xor(e, 2);
            e += __shfl_xor(e, 4);
            e += __shfl_xor(e, 8);
            if (lane16 == 0) sh.b.en[sl] = e;
        }
        __syncthreads();

        // local softmax partials over the 64 energies (one wave)
        if (tid < 64) {
            float e = sh.b.en[tid];
            float m = e;
            #pragma unroll
            for (int off = 32; off; off >>= 1) m = fmaxf(m, __shfl_xor(m, off));
            float p = expf(e - m);
            float ss = p;
            #pragma unroll
            for (int off = 32; off; off >>= 1) ss += __shfl_xor(ss, off);
            sh.b.en[tid] = p;
            if (tid == 0) { sh.b.mS[0] = m; sh.b.mS[1] = ss; }
        }
        __syncthreads();

        // partial ctx over this chunk
        {
            int v = tid & 127, half = tid >> 7;
            float a = 0.f;
            int sl0 = half * 32;
            #pragma unroll 4
            for (int sl = sl0; sl < sl0 + 32; ++sl)
                a += sh.b.en[sl] * values[((size_t)(s0 + sl) * BB + b) * VALD + v];
            sh.b.cp[half][v] = a;
        }
        __syncthreads();

        float* P = &partial[(size_t)(b * 8 + chunk) * PSTRIDE];
        if (tid < VALD) P[tid] = sh.b.cp[0][tid] + sh.b.cp[1][tid];
        else if (tid == VALD) { P[VALD] = sh.b.mS[0]; P[VALD + 1] = sh.b.mS[1]; }
        __syncthreads();
    }
}

// ---------------- gates phase: combine partials -> ctx_s, GEMM, cell --------
__device__ void gates_phase(SharedAll& sh, int bid, int tid,
                            const int* __restrict__ xt,
                            const float* __restrict__ Wih,
                            const float* __restrict__ Whh,
                            const float* E2, const float* partial,
                            const float* hprev, float* hout, float* cst,
                            float* ctxg_out)
{
    const int bi = bid & 7;               // 8 b-tiles
    const int nj = bid >> 3;              // 0..18
    const int b0 = bi * GTB;
    const int n0 = nj * GTN;
    const int nl = tid & 15, bl = tid >> 4;

    // combine weights from per-chunk (m, S)
    {
        int bb = tid >> 3, j = tid & 7;   // 256 threads == 32*8
        const float* P = &partial[(size_t)((b0 + bb) * 8 + j) * PSTRIDE];
        sh.g.u.c.m[bb][j] = P[VALD];
        sh.g.u.c.S[bb][j] = P[VALD + 1];
    }
    __syncthreads();
    if (tid < GTB) {
        float M = -1e30f;
        #pragma unroll
        for (int j = 0; j < 8; ++j) M = fmaxf(M, sh.g.u.c.m[tid][j]);
        float T = 0.f;
        #pragma unroll
        for (int j = 0; j < 8; ++j) T += sh.g.u.c.S[tid][j] * expf(sh.g.u.c.m[tid][j] - M);
        float inv = 1.f / T;
        #pragma unroll
        for (int j = 0; j < 8; ++j) sh.g.u.c.w[tid][j] = expf(sh.g.u.c.m[tid][j] - M) * inv;
    }
    __syncthreads();

    // combined ctx rows for this tile's 32 b's
    for (int e = tid; e < GTB * KEYD; e += 256) {
        int bb = e >> 7, v = e & 127;
        const float* P = &partial[(size_t)((b0 + bb) * 8) * PSTRIDE + v];
        float s = 0.f;
        #pragma unroll
        for (int j = 0; j < 8; ++j) s += sh.g.u.c.w[bb][j] * P[(size_t)j * PSTRIDE];
        sh.g.ctx_s[bb][v] = s;
        if (nj == 0) ctxg_out[(b0 + bb) * VALD + v] = s;   // global copy for logits
    }
    __syncthreads();

    const int b_0 = b0 + bl, b_1 = b0 + bl + 16;
    const int n = n0 + nl;
    const bool nok = (n < HIDD);

    float acc0[4], acc1[4];
    {
        int x0 = xt[b_0], x1 = xt[b_1];
        #pragma unroll
        for (int g = 0; g < 4; ++g) {
            acc0[g] = nok ? E2[x0 * GDIM + g * HIDD + n] : 0.f;
            acc1[g] = nok ? E2[x1 * GDIM + g * HIDD + n] : 0.f;
        }
    }

    for (int k0 = 0; k0 < KTOT; k0 += GBK) {
        #pragma unroll
        for (int r = 0; r < 4; ++r) {
            int e = r * 256 + tid;
            int bb = e >> 5, kk = e & 31;
            int k = k0 + kk;
            float v = 0.f;
            if (k < KEYD) v = sh.g.ctx_s[bb][k];
            else if (k < KTOT) v = hprev[(b0 + bb) * HIDD + (k - KEYD)];
            sh.g.u.k.As[bb][kk] = v;
        }
        #pragma unroll
        for (int r = 0; r < 8; ++r) {
            int e = r * 256 + tid;
            int g = e >> 9, rem = e & 511;
            int nn = rem >> 5, kk = rem & 31;
            int k = k0 + kk, jn = n0 + nn;
            float v = 0.f;
            if (k < KTOT && jn < HIDD) {
                int j = g * HIDD + jn;
                v = (k < KEYD) ? Wih[(size_t)j * WIH_LD + EMBD + k]
                               : Whh[(size_t)j * HIDD + (k - KEYD)];
            }
            sh.g.u.k.Ws[g][nn][kk] = v;
        }
        __syncthreads();
        #pragma unroll
        for (int kk = 0; kk < GBK; ++kk) {
            float a0 = sh.g.u.k.As[bl][kk];
            float a1 = sh.g.u.k.As[bl + 16][kk];
            #pragma unroll
            for (int g = 0; g < 4; ++g) {
                float w = sh.g.u.k.Ws[g][nl][kk];
                acc0[g] += a0 * w;
                acc1[g] += a1 * w;
            }
        }
        __syncthreads();
    }

    if (nok) {
        {
            float ig = sigmoidf_(acc0[0]);
            float fg = sigmoidf_(acc0[1]);
            float gg = tanhf(acc0[2]);
            float og = sigmoidf_(acc0[3]);
            float cn = fg * cst[b_0 * HIDD + n] + ig * gg;
            cst[b_0 * HIDD + n] = cn;
            hout[b_0 * HIDD + n] = og * tanhf(cn);
        }
        {
            float ig = sigmoidf_(acc1[0]);
            float fg = sigmoidf_(acc1[1]);
            float gg = tanhf(acc1[2]);
            float og = sigmoidf_(acc1[3]);
            float cn = fg * cst[b_1 * HIDD + n] + ig * gg;
            cst[b_1 * HIDD + n] = cn;
            hout[b_1 * HIDD + n] = og * tanhf(cn);
        }
    }
}

// ---------------- logits: 1 block = 1 b ----------------
__device__ void logits_phase(SharedAll& sh, int tid, int b, int step,
                             const float* h, const float* ctxold,
                             const float* __restrict__ projw,
                             const float* __restrict__ projb,
                             float* out)
{
    for (int i = tid; i < HIDD; i += 256) sh.l.hrow[i] = h[b * HIDD + i];
    if (tid < VALD) sh.l.crow[tid] = ctxold[b * VALD + tid];
    __syncthreads();
    if (tid < NVOC * 8) {
        int v = tid >> 3, j = tid & 7;
        float s = 0.f;
        for (int k = j; k < KTOT; k += 8) {
            float a = (k < HIDD) ? sh.l.hrow[k] : sh.l.crow[k - HIDD];
            s += a * projw[v * KTOT + k];
        }
        sh.l.lp[v][j] = s;
    }
    __syncthreads();
    if (tid < NVOC) {
        float s = projb[tid];
        #pragma unroll
        for (int j = 0; j < 8; ++j) s += sh.l.lp[tid][j];
        out[((size_t)step * BB + b) * NVOC + tid] = s;
    }
}

// ---------------- the persistent cooperative mega-kernel ----------------
extern "C" __global__ void __launch_bounds__(256, 2) mega_decoder(
    const int* input, const float* keys, const float* values,
    const float* embedding, const float* phi_w, const float* phi_b,
    const float* h0, const float* c0, const float* Wih, const float* bih,
    const float* Whh, const float* bhh, const float* projw, const float* projb,
    float* out, float* ws)
{
    cg::grid_group grid = cg::this_grid();
    const int bid = blockIdx.x, tid = threadIdx.x;
    const int nblk = gridDim.x;
    __shared__ SharedAll sh;

    float* hb0     = ws;                     // 76800
    float* hb1     = hb0 + BB * HIDD;        // 76800  (holds h_init after P0)
    float* cst     = hb1 + BB * HIDD;        // 76800
    float* ctxg0   = cst + BB * HIDD;        // 32768
    float* ctxg1   = ctxg0 + BB * VALD;      // 32768
    float* E2      = ctxg1 + BB * VALD;      // 39600
    float* phi_wT  = E2 + NVOC * GDIM;       // 38400
    float* partial = phi_wT + HIDD * KEYD;   // 2048*132

    // ---- P0: one-time precompute ----
    for (int i = bid * 256 + tid; i < KEYD * HIDD; i += nblk * 256) {
        int k = i / HIDD, ii = i - k * HIDD;
        phi_wT[ii * KEYD + k] = phi_w[i];
    }
    for (int i = bid * 256 + tid; i < BB * HIDD; i += nblk * 256) {
        int ii = i % HIDD;
        hb1[i] = h0[ii];
        cst[i] = c0[ii];
    }
    if (bid < NVOC) {   // E2[v][j] = b_ih[j]+b_hh[j]+emb[v]·W_ih[j][:400]
        for (int i = tid; i < EMBD; i += 256) sh.p.es[i] = embedding[bid * EMBD + i];
        __syncthreads();
        for (int j = tid; j < GDIM; j += 256) {
            const float* wr = &Wih[(size_t)j * WIH_LD];
            float s0 = 0.f, s1 = 0.f, s2 = 0.f, s3 = 0.f;
            for (int e = 0; e < EMBD; e += 4) {
                s0 += sh.p.es[e]     * wr[e];
                s1 += sh.p.es[e + 1] * wr[e + 1];
                s2 += sh.p.es[e + 2] * wr[e + 2];
                s3 += sh.p.es[e + 3] * wr[e + 3];
            }
            E2[bid * GDIM + j] = bih[j] + bhh[j] + ((s0 + s1) + (s2 + s3));
        }
    }
    grid.sync();

    // ---- P1: partials for ctx(-1) = attend(h_init) ----
    attn_phase(sh, bid, tid, keys, values, phi_wT, phi_b, hb1, partial);
    grid.sync();

    // ---- main loop ----
    #pragma unroll 1
    for (int t = 0; t < TT; ++t) {
        float* h_t    = (t & 1) ? hb1 : hb0;      // h(t)
        float* h_tm1  = (t & 1) ? hb0 : hb1;      // h(t-1)  (t=0 -> h_init)
        float* cg_t   = (t & 1) ? ctxg1 : ctxg0;  // ctx(t-1) written here
        float* cg_tm1 = (t & 1) ? ctxg0 : ctxg1;  // ctx(t-2) (for logits(t-1))

        // Phase A: gates tiles + logits(t-1) on otherwise-idle blocks
        if (bid < N_GATES) {
            gates_phase(sh, bid, tid, input + t * BB, Wih, Whh, E2, partial,
                        h_tm1, h_t, cst, cg_t);
        } else if (bid < N_GATES + BB) {
            if (t > 0)
                logits_phase(sh, tid, bid - N_GATES, t - 1, h_tm1, cg_tm1,
                             projw, projb, out);
        }
        grid.sync();

        // Phase B: attention partials for ctx(t)
        if (t < TT - 1) {
            attn_phase(sh, bid, tid, keys, values, phi_wT, phi_b, h_t, partial);
            grid.sync();
        }
    }

    // ---- final logits for t=255: h(255)=hb1, ctx(254)=ctxg1 ----
    if (bid < BB)
        logits_phase(sh, tid, bid, TT - 1, hb1, ctxg1, projw, projb, out);
}

// =====================================================================
// Fallback path (R1 structure — proven correct/passing) in case the
// cooperative launch is refused. Never used if coop launch succeeds.
// =====================================================================
__global__ __launch_bounds__(256) void fb_e2(
    const float* __restrict__ emb, const float* __restrict__ Wih,
    const float* __restrict__ bih, const float* __restrict__ bhh,
    float* __restrict__ E2)
{
    __shared__ float es[EMBD];
    const int v = blockIdx.x;
    for (int i = threadIdx.x; i < EMBD; i += 256) es[i] = emb[v * EMBD + i];
    __syncthreads();
    for (int j = threadIdx.x; j < GDIM; j += 256) {
        float s = bih[j] + bhh[j];
        const float* wr = &Wih[(size_t)j * WIH_LD];
        #pragma unroll 4
        for (int e = 0; e < EMBD; ++e) s += es[e] * wr[e];
        E2[v * GDIM + j] = s;
    }
}

__global__ __launch_bounds__(256) void fb_init(
    const float* __restrict__ phi_w, const float* __restrict__ h0,
    const float* __restrict__ c0,
    float* __restrict__ phi_wT, float* __restrict__ h, float* __restrict__ c)
{
    int i = blockIdx.x * 256 + threadIdx.x;
    if (i < KEYD * HIDD) {
        int k = i / HIDD, ii = i % HIDD;
        phi_wT[ii * KEYD + k] = phi_w[i];
    }
    if (i < BB * HIDD) {
        int ii = i % HIDD;
        h[i] = h0[ii];
        c[i] = c0[ii];
    }
}

#define FTB 16
#define FTN 16
#define FBK 32
__global__ __launch_bounds__(256) void fb_lstm(
    const int* __restrict__ xt, const float* __restrict__ Wih,
    const float* __restrict__ Whh, const float* __restrict__ E2,
    const float* __restrict__ ctx, const float* __restrict__ h_in,
    float* __restrict__ h_out, float* __restrict__ c)
{
    __shared__ float As[FTB][FBK + 1];
    __shared__ float Ws[4][FTN][FBK + 1];
    const int tid = threadIdx.x;
    const int nl = tid & 15;
    const int bl = tid >> 4;
    const int b0 = blockIdx.x * FTB;
    const int n0 = blockIdx.y * FTN;
    const int b = b0 + bl;
    const int n = n0 + nl;
    const bool valid = (n < HIDD);

    const int xb = xt[b];
    float acc[4];
    #pragma unroll
    for (int g = 0; g < 4; ++g)
        acc[g] = valid ? E2[xb * GDIM + g * HIDD + n] : 0.f;

    for (int k0 = 0; k0 < KTOT; k0 += FBK) {
        #pragma unroll
        for (int r = 0; r < 2; ++r) {
            int e = r * 256 + tid;
            int bb = e >> 5, kk = e & 31;
            int k = k0 + kk;
            float vv = 0.f;
            if (k < KTOT) {
                int gb = b0 + bb;
                vv = (k < VALD) ? ctx[gb * VALD + k] : h_in[gb * HIDD + (k - VALD)];
            }
            As[bb][kk] = vv;
        }
        #pragma unroll
        for (int r = 0; r < 8; ++r) {
            int e = r * 256 + tid;
            int g = e >> 9;
            int rem = e & 511;
            int nn = rem >> 5, kk = rem & 31;
            int k = k0 + kk;
            int jn = n0 + nn;
            float vv = 0.f;
            if (k < KTOT && jn < HIDD) {
                int j = g * HIDD + jn;
                vv = (k < VALD) ? Wih[(size_t)j * WIH_LD + EMBD + k]
                               : Whh[(size_t)j * HIDD + (k - VALD)];
            }
            Ws[g][nn][kk] = vv;
        }
        __syncthreads();
        #pragma unroll
        for (int kk = 0; kk < FBK; ++kk) {
            float a = As[bl][kk];
            #pragma unroll
            for (int g = 0; g < 4; ++g) acc[g] += a * Ws[g][nl][kk];
        }
        __syncthreads();
    }

    if (valid) {
        float ig = sigmoidf_(acc[0]);
        float fg = sigmoidf_(acc[1]);
        float gg = tanhf(acc[2]);
        float og = sigmoidf_(acc[3]);
        float cn = fg * c[b * HIDD + n] + ig * gg;
        c[b * HIDD + n] = cn;
        h_out[b * HIDD + n] = og * tanhf(cn);
    }
}

__global__ __launch_bounds__(512) void fb_attn(
    const float* __restrict__ keys, const float* __restrict__ values,
    const float* __restrict__ phi_wT, const float* __restrict__ phi_b,
    const float* __restrict__ projw, const float* __restrict__ projb,
    const float* __restrict__ h, float* __restrict__ ctx,
    float* __restrict__ out, int do_ctx)
{
    __shared__ float hh[HIDD];
    __shared__ float cx[VALD];
    __shared__ __align__(16) float q[KEYD];
    __shared__ float en[SS];
    __shared__ float qp[4][KEYD];
    __shared__ float lp[NVOC][8];
    __shared__ float cp[4][VALD];
    __shared__ float redm[8];
    __shared__ float reds[8];

    const int t = threadIdx.x;
    const int b = blockIdx.x;

    if (t < HIDD) hh[t] = h[b * HIDD + t];
    if (t < VALD) cx[t] = ctx[b * VALD + t];
    __syncthreads();

    if (out != nullptr) {
        if (t < NVOC * 8) {
            int v = t >> 3, j = t & 7;
            float s = 0.f;
            for (int k = j; k < KTOT; k += 8) {
                float a = (k < HIDD) ? hh[k] : cx[k - HIDD];
                s += a * projw[v * KTOT + k];
            }
            lp[v][j] = s;
        }
        __syncthreads();
        if (t < NVOC) {
            float s = projb[t];
            #pragma unroll
            for (int j = 0; j < 8; ++j) s += lp[t][j];
            out[b * NVOC + t] = s;
        }
    }

    if (!do_ctx) return;

    {
        int k = t & 127, qtr = t >> 7;
        float s = 0.f;
        int i0 = qtr * 75;
        for (int i = i0; i < i0 + 75; ++i) s += hh[i] * phi_wT[i * KEYD + k];
        qp[qtr][k] = s;
    }
    __syncthreads();
    if (t < KEYD) q[t] = phi_b[t] + qp[0][t] + qp[1][t] + qp[2][t] + qp[3][t];
    __syncthreads();

    {
        const int lane16 = t & 15;
        const int grp = t >> 4;
        const float4* q4 = reinterpret_cast<const float4*>(q);
        #pragma unroll 2
        for (int it = 0; it < 16; ++it) {
            int s = it * 32 + grp;
            const float4* kp = reinterpret_cast<const float4*>(&keys[((size_t)s * BB + b) * KEYD]);
            int kb = lane16 * 2;
            float4 k0 = kp[kb], k1 = kp[kb + 1];
            float4 q0 = q4[kb], q1 = q4[kb + 1];
            float e = k0.x * q0.x + k0.y * q0.y + k0.z * q0.z + k0.w * q0.w
                    + k1.x * q1.x + k1.y * q1.y + k1.z * q1.z + k1.w * q1.w;
            e += __shfl_xor(e, 1);
            e += __shfl_xor(e, 2);
            e += __shfl_xor(e, 4);
            e += __shfl_xor(e, 8);
            if (lane16 == 0) en[s] = e;
        }
    }
    __syncthreads();

    {
        float m = en[t];
        #pragma unroll
        for (int off = 32; off; off >>= 1) m = fmaxf(m, __shfl_xor(m, off));
        int w = t >> 6;
        if ((t & 63) == 0) redm[w] = m;
        __syncthreads();
        m = redm[0];
        #pragma unroll
        for (int i = 1; i < 8; ++i) m = fmaxf(m, redm[i]);
        float e = expf(en[t] - m);
        float ss = e;
        #pragma unroll
        for (int off = 32; off; off >>= 1) ss += __shfl_xor(ss, off);
        if ((t & 63) == 0) reds[w] = ss;
        __syncthreads();
        float Ssum = reds[0];
        #pragma unroll
        for (int i = 1; i < 8; ++i) Ssum += reds[i];
        en[t] = e * (1.f / Ssum);
    }
    __syncthreads();

    {
        int v = t & 127, qtr = t >> 7;
        float a = 0.f;
        int s0 = qtr * 128;
        #pragma unroll 4
        for (int s = s0; s < s0 + 128; ++s)
            a += en[s] * values[((size_t)s * BB + b) * VALD + v];
        cp[qtr][v] = a;
    }
    __syncthreads();
    if (t < VALD) ctx[b * VALD + t] = cp[0][t] + cp[1][t] + cp[2][t] + cp[3][t];
}

// =====================================================================
extern "C" void kernel_launch(void* const* d_in, const int* in_sizes, int n_in,
                              void* d_out, int out_size, void* d_ws, size_t ws_size,
                              hipStream_t stream)
{
    const int*   input     = (const int*)  d_in[0];
    const float* keys      = (const float*)d_in[1];
    const float* values    = (const float*)d_in[2];
    const float* embedding = (const float*)d_in[3];
    const float* phi_w     = (const float*)d_in[4];
    const float* phi_b     = (const float*)d_in[5];
    const float* h0        = (const float*)d_in[6];
    const float* c0        = (const float*)d_in[7];
    const float* W_ih      = (const float*)d_in[8];
    const float* b_ih      = (const float*)d_in[9];
    const float* W_hh      = (const float*)d_in[10];
    const float* b_hh      = (const float*)d_in[11];
    const float* proj_w    = (const float*)d_in[12];
    const float* proj_b    = (const float*)d_in[13];
    float* out = (float*)d_out;
    float* wsf = (float*)d_ws;

    // ---- try the cooperative mega-kernel ----
    int dev = 0;
    (void)hipGetDevice(&dev);
    int nCU = 0;
    (void)hipDeviceGetAttribute(&nCU, hipDeviceAttributeMultiprocessorCount, dev);
    int maxblk = 0;
    hipError_t oe = hipOccupancyMaxActiveBlocksPerMultiprocessor(
        &maxblk, (const void*)mega_decoder, 256, 0);
    bool coop_ok = (oe == hipSuccess) && nCU > 0 && (maxblk * nCU >= NGRID);

    if (coop_ok) {
        void* args[16];
        args[0]  = (void*)&input;     args[1]  = (void*)&keys;
        args[2]  = (void*)&values;    args[3]  = (void*)&embedding;
        args[4]  = (void*)&phi_w;     args[5]  = (void*)&phi_b;
        args[6]  = (void*)&h0;        args[7]  = (void*)&c0;
        args[8]  = (void*)&W_ih;      args[9]  = (void*)&b_ih;
        args[10] = (void*)&W_hh;      args[11] = (void*)&b_hh;
        args[12] = (void*)&proj_w;    args[13] = (void*)&proj_b;
        args[14] = (void*)&out;       args[15] = (void*)&wsf;
        hipError_t le = hipLaunchCooperativeKernel((const void*)mega_decoder,
                                                   dim3(NGRID), dim3(256),
                                                   args, 0, stream);
        if (le == hipSuccess) return;
    }

    // ---- fallback: proven multi-kernel path ----
    float* hA     = wsf;
    float* hB     = hA + BB * HIDD;
    float* c      = hB + BB * HIDD;
    float* ctx    = c + BB * HIDD;
    float* E2     = ctx + BB * VALD;
    float* phi_wT = E2 + NVOC * GDIM;

    fb_e2<<<NVOC, 256, 0, stream>>>(embedding, W_ih, b_ih, b_hh, E2);
    fb_init<<<(BB * HIDD + 255) / 256, 256, 0, stream>>>(phi_w, h0, c0, phi_wT, hA, c);
    fb_attn<<<BB, 512, 0, stream>>>(keys, values, phi_wT, phi_b, proj_w, proj_b,
                                    hA, ctx, nullptr, 1);
    float* hin = hA;
    float* hout = hB;
    for (int t = 0; t < TT; ++t) {
        fb_lstm<<<dim3(BB / FTB, (HIDD + FTN - 1) / FTN), 256, 0, stream>>>(
            input + t * BB, W_ih, W_hh, E2, ctx, hin, hout, c);
        fb_attn<<<BB, 512, 0, stream>>>(keys, values, phi_wT, phi_b, proj_w, proj_b,
                                        hout, ctx, out + (size_t)t * BB * NVOC,
                                        (t < TT - 1) ? 1 : 0);
        float* tmp = hin; hin = hout; hout = tmp;
    }
}